// Round 1
// 71.852 us; speedup vs baseline: 1.0112x; 1.0112x over previous
//
#include <hip/hip_runtime.h>
#include <math.h>

#define DEPTH 5

// Full algebraic collapse:
//   state after RY embedding: p = (c0c1, c0s1, s0c1, s0s1), c=cos(x/2), s=sin(x/2)
//   z = <Z0> = p^T A p,  A = Re(U^H D U)  (4x4 real symmetric, weights-only)
//   p p^T = (v0 v0^T) (x) (v1 v1^T), and vv^T entries are affine in (1,cosx,sinx)
//   => t = -log2e*(w*z+b) = (1,C0,S0) . B . (1,C1,S1)^T   (9 coeffs, fc+sigmoid folded)
//   out = rcp(1 + exp2(t))
// Per sample: 2 x __sincosf + 8 FMA + v_exp + v_rcp  (~16 ops vs ~60 before,
// and the precise-division sequence is gone).
// Loads: lane-interleaved so each float4 load is 16B/lane consecutive (fully
// coalesced), stores are 8B/lane consecutive float2.

__device__ __forceinline__ float eval_sample(const float B[9], float x0, float x1) {
    float s0, c0, s1, c1;
    __sincosf(x0, &s0, &c0);
    __sincosf(x1, &s1, &c1);
    float u0 = fmaf(B[2], s1, fmaf(B[1], c1, B[0]));
    float u1 = fmaf(B[5], s1, fmaf(B[4], c1, B[3]));
    float u2 = fmaf(B[8], s1, fmaf(B[7], c1, B[6]));
    float t = fmaf(s0, u2, fmaf(c0, u1, u0));     // t = -log2e*(w*z + b)
    return __builtin_amdgcn_rcpf(1.0f + __builtin_amdgcn_exp2f(t));
}

__global__ __launch_bounds__(256) void hqnet_kernel(
    const float* __restrict__ x, const float* __restrict__ qw,
    const float* __restrict__ fcw, const float* __restrict__ fcb,
    float* __restrict__ out, int n_samples)
{
    __shared__ float uRe[4][4], uIm[4][4];
    __shared__ float sA[4][4];
    __shared__ float sB[9];

    // ---- Stage 1: lanes 0..3 build U columns (5x RX/RX/CNOT), as before ----
    if (threadIdx.x < 4) {
        const int j = threadIdx.x;
        float cr[4], ci[4];
        #pragma unroll
        for (int i = 0; i < 4; i++) { cr[i] = (i == j) ? 1.f : 0.f; ci[i] = 0.f; }
        #pragma unroll
        for (int l = 0; l < DEPTH; l++) {
            float c0, s0, c1, s1;
            __sincosf(qw[2 * l + 0] * 0.5f, &s0, &c0);
            __sincosf(qw[2 * l + 1] * 0.5f, &s1, &c1);
            #pragma unroll
            for (int b = 0; b < 2; b++) {   // RX wire 0: pairs (0,2),(1,3)
                float ar = cr[b], ai = ci[b], br = cr[b + 2], bi = ci[b + 2];
                cr[b]     = c0 * ar + s0 * bi;  ci[b]     = c0 * ai - s0 * br;
                cr[b + 2] = c0 * br + s0 * ai;  ci[b + 2] = c0 * bi - s0 * ar;
            }
            #pragma unroll
            for (int a = 0; a < 2; a++) {   // RX wire 1: pairs (0,1),(2,3)
                int r0 = 2 * a, r1 = 2 * a + 1;
                float ar = cr[r0], ai = ci[r0], br = cr[r1], bi = ci[r1];
                cr[r0] = c1 * ar + s1 * bi;  ci[r0] = c1 * ai - s1 * br;
                cr[r1] = c1 * br + s1 * ai;  ci[r1] = c1 * bi - s1 * ar;
            }
            float tr = cr[2], ti = ci[2];   // CNOT: swap |10>,|11>
            cr[2] = cr[3]; ci[2] = ci[3];
            cr[3] = tr;    ci[3] = ti;
        }
        #pragma unroll
        for (int i = 0; i < 4; i++) { uRe[i][j] = cr[i]; uIm[i][j] = ci[i]; }
    }
    __syncthreads();

    // ---- Stage 2: 16 threads form A = Re(U^H D U), D = diag(1,1,-1,-1) ----
    if (threadIdx.x < 16) {
        const int i = threadIdx.x >> 2, j = threadIdx.x & 3;
        float a = 0.f;
        a += uRe[0][i] * uRe[0][j] + uIm[0][i] * uIm[0][j];
        a += uRe[1][i] * uRe[1][j] + uIm[1][i] * uIm[1][j];
        a -= uRe[2][i] * uRe[2][j] + uIm[2][i] * uIm[2][j];
        a -= uRe[3][i] * uRe[3][j] + uIm[3][i] * uIm[3][j];
        sA[i][j] = a;
    }
    __syncthreads();

    // ---- Stage 3: thread 0 folds half-angle identities + fc + sigmoid into B ----
    if (threadIdx.x == 0) {
        // blocks m_{a0b0}[a1][b1] = A[2a0+a1][2b0+b1]; per-block 3-vector over (1,C,S)
        float h[2][2][3];
        #pragma unroll
        for (int a0 = 0; a0 < 2; a0++)
            #pragma unroll
            for (int b0 = 0; b0 < 2; b0++) {
                float m00 = sA[2 * a0 + 0][2 * b0 + 0], m01 = sA[2 * a0 + 0][2 * b0 + 1];
                float m10 = sA[2 * a0 + 1][2 * b0 + 0], m11 = sA[2 * a0 + 1][2 * b0 + 1];
                h[a0][b0][0] = 0.5f * (m00 + m11);
                h[a0][b0][1] = 0.5f * (m00 - m11);
                h[a0][b0][2] = 0.5f * (m01 + m10);
            }
        const float scale = -1.44269504f * fcw[0];  // fold w and sigmoid's log2e
        #pragma unroll
        for (int l = 0; l < 3; l++) {
            sB[0 * 3 + l] = scale * 0.5f * (h[0][0][l] + h[1][1][l]);
            sB[1 * 3 + l] = scale * 0.5f * (h[0][0][l] - h[1][1][l]);
            sB[2 * 3 + l] = scale * 0.5f * (h[0][1][l] + h[1][0][l]);
        }
        sB[0] += -1.44269504f * fcb[0];             // fold bias
    }
    __syncthreads();

    float B[9];
    #pragma unroll
    for (int k = 0; k < 9; k++) B[k] = sB[k];       // broadcast LDS reads

    // ---- Main: lane-interleaved, 4 coalesced float4 (= 8 samples) per thread ----
    const int tid  = blockIdx.x * blockDim.x + threadIdx.x;
    const int wave = tid >> 6;
    const int lane = threadIdx.x & 63;
    const int nF4  = n_samples >> 1;                // one float4 of x = 2 samples
    const int f0   = wave * 256 + lane;
    const float4* __restrict__ xv = (const float4*)x;
    float2* __restrict__ ov = (float2*)out;

    if (f0 + 192 < nF4) {                           // all 4 indices in range
        float4 v0 = xv[f0];
        float4 v1 = xv[f0 + 64];
        float4 v2 = xv[f0 + 128];
        float4 v3 = xv[f0 + 192];
        float2 r0 = make_float2(eval_sample(B, v0.x, v0.y), eval_sample(B, v0.z, v0.w));
        float2 r1 = make_float2(eval_sample(B, v1.x, v1.y), eval_sample(B, v1.z, v1.w));
        float2 r2 = make_float2(eval_sample(B, v2.x, v2.y), eval_sample(B, v2.z, v2.w));
        float2 r3 = make_float2(eval_sample(B, v3.x, v3.y), eval_sample(B, v3.z, v3.w));
        ov[f0]       = r0;
        ov[f0 + 64]  = r1;
        ov[f0 + 128] = r2;
        ov[f0 + 192] = r3;
    } else {
        #pragma unroll
        for (int q = 0; q < 4; q++) {
            int f = f0 + 64 * q;
            if (f < nF4) {
                float4 v = xv[f];
                ov[f] = make_float2(eval_sample(B, v.x, v.y), eval_sample(B, v.z, v.w));
            }
        }
    }
    // odd trailing sample (not hit for N = 2^21)
    if ((n_samples & 1) && tid == 0) {
        int last = n_samples - 1;
        out[last] = eval_sample(B, x[2 * last], x[2 * last + 1]);
    }
}

extern "C" void kernel_launch(void* const* d_in, const int* in_sizes, int n_in,
                              void* d_out, int out_size, void* d_ws, size_t ws_size,
                              hipStream_t stream) {
    const float* x   = (const float*)d_in[0];  // [N,2]
    const float* qw  = (const float*)d_in[1];  // [5,2]
    const float* fcw = (const float*)d_in[2];  // [1,1]
    const float* fcb = (const float*)d_in[3];  // [1]
    float* out = (float*)d_out;                // [N]

    const int n_samples = in_sizes[0] / 2;
    const int nF4 = n_samples >> 1;
    int nWaves = (nF4 + 255) >> 8;             // 256 float4s per wave
    if (nWaves < 1) nWaves = 1;
    const int n_threads = nWaves * 64;
    const int block = 256;
    const int grid = (n_threads + block - 1) / block;
    hqnet_kernel<<<grid, block, 0, stream>>>(x, qw, fcw, fcb, out, n_samples);
}